// Round 1
// baseline (3327.999 us; speedup 1.0000x reference)
//
#include <hip/hip_runtime.h>
#include <hip/hip_cooperative_groups.h>

namespace cg = cooperative_groups;

#define KCOLS 7
#define MCOLS 8

// Persistent cooperative kernel: runs the entire Sinkhorn loop + final plan
// write in ONE launch. b (8 f64) lives in registers of every thread; each
// iteration is one fused pass over P computing column sums c_j = sum_i q_ij*a_i,
// with a grid.sync() between producing per-block partials and the redundant
// per-block reduction (identical f64 arithmetic in every block -> uniform
// convergence decision, no second sync needed; partials double-buffered by
// iteration parity).
__global__ __launch_bounds__(256, 2)
void sinkhorn_persistent(const float* __restrict__ P, float* __restrict__ out,
                         double* __restrict__ partials, int n, int nb) {
    cg::grid_group grid = cg::this_grid();
    const int tid = threadIdx.x;
    const int G = nb * 256;                 // total threads
    const int g0 = blockIdx.x * 256 + tid;  // global thread id
    const double inv_n = 1.0 / (double)n;
    const double fi = 1.0 / 1.1;            // GAMMA/(GAMMA+EPSILON)

    // Pb = [RHO*prior; 1-RHO], prior = CLUSTER_SIZES/100, RHO=1
    const double Pb[MCOLS] = {0.17, 0.14, 0.15, 0.12, 0.05, 0.13, 0.24, 0.0};

    double b[MCOLS], bprev[MCOLS];
#pragma unroll
    for (int j = 0; j < MCOLS; ++j) { b[j] = 0.125; bprev[j] = 0.125; }

    __shared__ double wred[4][MCOLS];   // per-wave partials (256 thr = 4 waves)
    __shared__ double red2[256];
    __shared__ double bn_sh[MCOLS];

    const int lane = tid & 63;
    const int wv = tid >> 6;

    int par = 0;
    bool done = false;

    for (int it = 0; it < 50 && !done; ++it) {
        // ---- phase 1: c-partials with current b ----
        double acc[MCOLS];
#pragma unroll
        for (int j = 0; j < MCOLS; ++j) acc[j] = 0.0;

        for (int i = g0; i < n; i += G) {
            const float* row = P + (size_t)i * KCOLS;
            float p[KCOLS];
#pragma unroll
            for (int j = 0; j < KCOLS; ++j) p[j] = row[j];
            float mx = p[0];
#pragma unroll
            for (int j = 1; j < KCOLS; ++j) mx = fmaxf(mx, p[j]);
            float s = 0.0f;
#pragma unroll
            for (int j = 0; j < KCOLS; ++j) s += __expf(p[j] - mx);
            const float ls10 = 10.0f * __logf(s);
            float q[KCOLS];
            double dot = b[KCOLS];  // Q[:,7] = 1
#pragma unroll
            for (int j = 0; j < KCOLS; ++j) {
                q[j] = __expf(fmaf(10.0f, p[j] - mx, -ls10));  // softmax^10
                dot = fma((double)q[j], b[j], dot);
            }
            const double a = inv_n / dot;
#pragma unroll
            for (int j = 0; j < KCOLS; ++j) acc[j] = fma((double)q[j], a, acc[j]);
            acc[KCOLS] += a;
        }

        // wave-level reduce (no barriers), then 1 syncthreads, write block partial
#pragma unroll
        for (int j = 0; j < MCOLS; ++j) {
            double v = acc[j];
#pragma unroll
            for (int off = 32; off > 0; off >>= 1) v += __shfl_down(v, off, 64);
            if (lane == 0) wred[wv][j] = v;
        }
        __syncthreads();
        if (tid < MCOLS) {
            double v = wred[0][tid] + wred[1][tid] + wred[2][tid] + wred[3][tid];
            partials[((size_t)par * nb + blockIdx.x) * MCOLS + tid] = v;
        }
        grid.sync();

        // ---- phase 2: every block redundantly reduces all partials ----
        {
            const double* pp = partials + (size_t)par * nb * MCOLS;
            const int j = tid & 7;
            const int idx = tid >> 3;
            double s2 = 0.0;
            for (int bb = idx; bb < nb; bb += 32) s2 += pp[(size_t)bb * MCOLS + j];
            red2[tid] = s2;
            __syncthreads();
            if (tid < MCOLS) {
                double c = 0.0;
#pragma unroll
                for (int i2 = 0; i2 < 32; ++i2) c += red2[i2 * MCOLS + tid];
                double bnj = 0.0;
                if (tid < KCOLS) bnj = pow(Pb[tid] / c, fi);  // semi: b[:7]^fi; b[7]=0/c=0
                bn_sh[tid] = bnj;
            }
            __syncthreads();
            double err2 = 0.0;
#pragma unroll
            for (int j2 = 0; j2 < MCOLS; ++j2) {
                const double bn = bn_sh[j2];
                const double d = bn - b[j2];
                err2 += d * d;
                bprev[j2] = b[j2];
                b[j2] = bn;
            }
            done = (err2 <= 1e-12);  // ||b-last_b|| <= 1e-6
            par ^= 1;
        }
    }

    // ---- final: plan[i,j] = q_ij * b_j / (q_i . bprev) ----
    for (int i = g0; i < n; i += G) {
        const float* row = P + (size_t)i * KCOLS;
        float p[KCOLS];
#pragma unroll
        for (int j = 0; j < KCOLS; ++j) p[j] = row[j];
        float mx = p[0];
#pragma unroll
        for (int j = 1; j < KCOLS; ++j) mx = fmaxf(mx, p[j]);
        float s = 0.0f;
#pragma unroll
        for (int j = 0; j < KCOLS; ++j) s += __expf(p[j] - mx);
        const float ls10 = 10.0f * __logf(s);
        float q[KCOLS];
        double dot = bprev[KCOLS];
#pragma unroll
        for (int j = 0; j < KCOLS; ++j) {
            q[j] = __expf(fmaf(10.0f, p[j] - mx, -ls10));
            dot = fma((double)q[j], bprev[j], dot);
        }
        const double r = 1.0 / dot;  // n*a
        float* orow = out + (size_t)i * KCOLS;
#pragma unroll
        for (int j = 0; j < KCOLS; ++j) orow[j] = (float)((double)q[j] * b[j] * r);
    }
}

extern "C" void kernel_launch(void* const* d_in, const int* in_sizes, int n_in,
                              void* d_out, int out_size, void* d_ws, size_t ws_size,
                              hipStream_t stream) {
    (void)n_in; (void)out_size;
    const float* P = (const float*)d_in[0];
    float* out = (float*)d_out;
    const int n = in_sizes[0] / KCOLS;
    double* partials = (double*)d_ws;

    int dev = 0;
    hipGetDevice(&dev);
    int cus = 256;
    hipDeviceGetAttribute(&cus, hipDeviceAttributeMultiprocessorCount, dev);
    int maxb = 2;
    hipOccupancyMaxActiveBlocksPerMultiprocessor(&maxb, sinkhorn_persistent, 256, 0);
    if (maxb < 1) maxb = 1;

    long long blocks = (long long)maxb * cus;
    if (blocks > 1024) blocks = 1024;  // 8 rows/thread at n=2^21; caps barrier cost
    // ws holds 2 (parity) * blocks * 8 doubles
    while (blocks > 64 && (size_t)(2 * blocks * MCOLS * sizeof(double)) > ws_size)
        blocks >>= 1;
    int nb = (int)blocks;

    void* args[] = {(void*)&P, (void*)&out, (void*)&partials, (void*)&n, (void*)&nb};
    hipLaunchCooperativeKernel((void*)sinkhorn_persistent, dim3(nb), dim3(256),
                               args, 0, stream);
}

// Round 3
// 1999.477 us; speedup vs baseline: 1.6644x; 1.6644x over previous
//
#include <hip/hip_runtime.h>
#include <hip/hip_cooperative_groups.h>

namespace cg = cooperative_groups;

#define KCOLS 7
#define MCOLS 8
#define LDSCH 768     // 4-row chunks cached in LDS  (3072 rows, 48 KB)
#define CACHECH 1024  // total cached chunks incl. 256 register chunks (4096 rows)
#define NB_PREF 512

// round-to-nearest-even pack of two f32 into bf16x2 (lo=a, hi=b)
__device__ __forceinline__ uint32_t pk_bf16(float a, float b) {
    uint32_t ua = __float_as_uint(a), ub = __float_as_uint(b);
    ua += 0x7FFFu + ((ua >> 16) & 1u);
    ub += 0x7FFFu + ((ub >> 16) & 1u);
    return (ua >> 16) | (ub & 0xFFFF0000u);
}
__device__ __forceinline__ void unp(uint32_t u, float& lo, float& hi) {
    lo = __uint_as_float(u << 16);
    hi = __uint_as_float(u & 0xFFFF0000u);
}
__device__ __forceinline__ float rcp_nr(float d) {
    float r = __builtin_amdgcn_rcpf(d);
    return fmaf(fmaf(-d, r, 1.0f), r, r);  // one Newton step -> ~1e-7 rel
}
// q = softmax(p)^10 (f32), sq = sum q
__device__ __forceinline__ void softmax10(const float* p, float* q, float& sq) {
    float mx = p[0];
#pragma unroll
    for (int j = 1; j < KCOLS; ++j) mx = fmaxf(mx, p[j]);
    float s = 0.0f;
#pragma unroll
    for (int j = 0; j < KCOLS; ++j) s += __expf(p[j] - mx);
    const float ls10 = 10.0f * __logf(s);
    sq = 0.0f;
#pragma unroll
    for (int j = 0; j < KCOLS; ++j) {
        q[j] = __expf(fmaf(10.0f, p[j] - mx, -ls10));
        sq += q[j];
    }
}

// setup: one 4-row chunk -> acc (b0 = 1/8 everywhere) + packed bf16 rows
__device__ __forceinline__ void setup_chunk(const float4* Pv, size_t f4base,
                                            float* acc, uint4* qq) {
    union { float4 v4[7]; float f[28]; } u;
#pragma unroll
    for (int i = 0; i < 7; ++i) u.v4[i] = Pv[f4base + i];
#pragma unroll
    for (int k = 0; k < 4; ++k) {
        float q[KCOLS], sq;
        softmax10(u.f + k * 7, q, sq);
        qq[k] = make_uint4(pk_bf16(q[0], q[1]), pk_bf16(q[2], q[3]),
                           pk_bf16(q[4], q[5]), pk_bf16(q[6], 1.0f));
        const float rr = rcp_nr(0.125f * (sq + 1.0f));
#pragma unroll
        for (int j = 0; j < KCOLS; ++j) acc[j] = fmaf(q[j], rr, acc[j]);
        acc[KCOLS] += rr;
    }
}

// iteration contribution of one cached (bf16-packed) row
__device__ __forceinline__ void cached_row(uint4 u, const float* bf, float* acc) {
    float f0, f1, f2, f3, f4, f5, f6, f7;
    unp(u.x, f0, f1); unp(u.y, f2, f3); unp(u.z, f4, f5); unp(u.w, f6, f7);
    float dot = f0 * bf[0];
    dot = fmaf(f1, bf[1], dot); dot = fmaf(f2, bf[2], dot);
    dot = fmaf(f3, bf[3], dot); dot = fmaf(f4, bf[4], dot);
    dot = fmaf(f5, bf[5], dot); dot = fmaf(f6, bf[6], dot);
    dot = fmaf(f7, bf[7], dot);
    const float rr = rcp_nr(dot);
    acc[0] = fmaf(f0, rr, acc[0]); acc[1] = fmaf(f1, rr, acc[1]);
    acc[2] = fmaf(f2, rr, acc[2]); acc[3] = fmaf(f3, rr, acc[3]);
    acc[4] = fmaf(f4, rr, acc[4]); acc[5] = fmaf(f5, rr, acc[5]);
    acc[6] = fmaf(f6, rr, acc[6]); acc[7] = fmaf(f7, rr, acc[7]);
}

// iteration contribution of one streamed chunk (recompute q from P)
__device__ __forceinline__ void stream_chunk(const float4* Pv, size_t f4base,
                                             const float* bf, float* acc) {
    union { float4 v4[7]; float f[28]; } u;
#pragma unroll
    for (int i = 0; i < 7; ++i) u.v4[i] = Pv[f4base + i];
#pragma unroll
    for (int k = 0; k < 4; ++k) {
        float q[KCOLS], sq;
        softmax10(u.f + k * 7, q, sq);
        float dot = bf[KCOLS];
#pragma unroll
        for (int j = 0; j < KCOLS; ++j) dot = fmaf(q[j], bf[j], dot);
        const float rr = rcp_nr(dot);
#pragma unroll
        for (int j = 0; j < KCOLS; ++j) acc[j] = fmaf(q[j], rr, acc[j]);
        acc[KCOLS] += rr;
    }
}

// final: one chunk -> plan
__device__ __forceinline__ void final_chunk(const float4* Pv, float4* Ov, size_t f4base,
                                            const float* bpf, const float* bfin) {
    union { float4 v4[7]; float f[28]; } u;
    union { float4 v4[7]; float f[28]; } o;
#pragma unroll
    for (int i = 0; i < 7; ++i) u.v4[i] = Pv[f4base + i];
#pragma unroll
    for (int k = 0; k < 4; ++k) {
        float q[KCOLS], sq;
        softmax10(u.f + k * 7, q, sq);
        float dot = bpf[KCOLS];
#pragma unroll
        for (int j = 0; j < KCOLS; ++j) dot = fmaf(q[j], bpf[j], dot);
        const float rr = rcp_nr(dot);
#pragma unroll
        for (int j = 0; j < KCOLS; ++j) o.f[k * 7 + j] = q[j] * bfin[j] * rr;
    }
#pragma unroll
    for (int i = 0; i < 7; ++i) Ov[f4base + i] = o.v4[i];
}

// Persistent cooperative Sinkhorn. Block owns rows [bx*rpb, bx*rpb+rpb).
// First 3072 rows cached bf16 in LDS, next 1024 in registers (4/thread),
// remainder (only if nb < NB_PREF) recomputed from P each iteration.
__global__ __launch_bounds__(256, 2)
void sinkhorn_v3(const float* __restrict__ P, float* __restrict__ out,
                 double* __restrict__ partials, int n, int nb, int rpb) {
    cg::grid_group grid = cg::this_grid();
    const int tid = threadIdx.x, bx = blockIdx.x;
    const int lane = tid & 63, wv = tid >> 6;
    const double inv_n = 1.0 / (double)n;
    const double fi = 1.0 / 1.1;  // GAMMA/(GAMMA+EPSILON)
    const double Pb[MCOLS] = {0.17, 0.14, 0.15, 0.12, 0.05, 0.13, 0.24, 0.0};

    __shared__ uint4 qsh[LDSCH * 4];     // 48 KB
    __shared__ double wred[4][MCOLS];
    __shared__ double red2[256];
    __shared__ double bn_sh[MCOLS];

    const int row0 = bx * rpb;           // rpb is a multiple of 4
    int rows_here = n - row0;
    if (rows_here > rpb) rows_here = rpb;
    if (rows_here < 0) rows_here = 0;
    const int nch = rows_here >> 2;                       // full 4-row chunks
    const int nlds = (nch < LDSCH) ? nch : LDSCH;
    const int ncached = (nch < CACHECH) ? nch : CACHECH;
    const size_t base4 = (size_t)(row0 >> 2) * 7;         // float4 index
    const float4* Pv = (const float4*)P;

    uint4 rq[4];                          // register-cached chunk (4 rows)
    const int crg = LDSCH + tid;
    const bool have_reg = (crg < ncached);

    // ---------------- setup pass: read P, cache q, fold iteration 1 --------
    float acc[MCOLS];
#pragma unroll
    for (int j = 0; j < MCOLS; ++j) acc[j] = 0.0f;

#pragma unroll
    for (int jj = 0; jj < 3; ++jj) {
        const int c = tid + 256 * jj;
        if (c < nlds) {
            uint4 qq[4];
            setup_chunk(Pv, base4 + (size_t)c * 7, acc, qq);
#pragma unroll
            for (int k = 0; k < 4; ++k) qsh[c * 4 + k] = qq[k];
        }
    }
    if (have_reg) setup_chunk(Pv, base4 + (size_t)crg * 7, acc, rq);
    for (int c = CACHECH + tid; c < nch; c += 256) {
        uint4 qq[4];
        setup_chunk(Pv, base4 + (size_t)c * 7, acc, qq);  // acc only
    }
    for (int r = (nch << 2) + tid; r < rows_here; r += 256) {  // scalar tail
        float p[KCOLS];
        const float* row = P + (size_t)(row0 + r) * KCOLS;
        for (int j = 0; j < KCOLS; ++j) p[j] = row[j];
        float q[KCOLS], sq;
        softmax10(p, q, sq);
        const float rr = rcp_nr(0.125f * (sq + 1.0f));
        for (int j = 0; j < KCOLS; ++j) acc[j] = fmaf(q[j], rr, acc[j]);
        acc[KCOLS] += rr;
    }

    // block reduce -> partials parity 0
#pragma unroll
    for (int j = 0; j < MCOLS; ++j) {
        float v = acc[j];
#pragma unroll
        for (int off = 32; off > 0; off >>= 1) v += __shfl_down(v, off, 64);
        if (lane == 0) wred[wv][j] = (double)v;
    }
    __syncthreads();
    if (tid < MCOLS)
        partials[(size_t)bx * MCOLS + tid] =
            wred[0][tid] + wred[1][tid] + wred[2][tid] + wred[3][tid];
    grid.sync();

    // ---------------- Sinkhorn loop ---------------------------------------
    double b[MCOLS], bprev[MCOLS];
#pragma unroll
    for (int j = 0; j < MCOLS; ++j) { b[j] = 0.125; bprev[j] = 0.125; }
    float bf[MCOLS];

    int par = 0;
    for (int it = 1; it <= 50; ++it) {
        // every block redundantly reduces partials[par] (identical f64 ->
        // identical b and uniform break decision across the grid)
        {
            const double* pp = partials + (size_t)par * nb * MCOLS;
            const int j8 = tid & 7, idx = tid >> 3;
            double s2 = 0.0;
            for (int bb = idx; bb < nb; bb += 32) s2 += pp[(size_t)bb * MCOLS + j8];
            red2[tid] = s2;
            __syncthreads();
            if (tid < MCOLS) {
                double c = 0.0;
#pragma unroll
                for (int i2 = 0; i2 < 32; ++i2) c += red2[i2 * MCOLS + tid];
                c *= inv_n;
                bn_sh[tid] = (tid < KCOLS) ? pow(Pb[tid] / c, fi) : 0.0;
            }
            __syncthreads();
        }
        double err2 = 0.0;
#pragma unroll
        for (int j = 0; j < MCOLS; ++j) {
            const double bn = bn_sh[j];
            const double d = bn - b[j];
            err2 += d * d;
            bprev[j] = b[j];
            b[j] = bn;
            bf[j] = (float)bn;
        }
        par ^= 1;
        if (err2 <= 1e-12 || it == 50) break;  // ||b-last_b|| <= 1e-6, cap 50

        // pass with new b: cached LDS rows + register rows + streamed rows
        float a2[MCOLS];
#pragma unroll
        for (int j = 0; j < MCOLS; ++j) a2[j] = 0.0f;
#pragma unroll
        for (int jj = 0; jj < 12; ++jj) {
            const int r = tid + 256 * jj;
            if (r < nlds * 4) cached_row(qsh[r], bf, a2);
        }
        if (have_reg) {
#pragma unroll
            for (int k = 0; k < 4; ++k) cached_row(rq[k], bf, a2);
        }
        for (int c = CACHECH + tid; c < nch; c += 256)
            stream_chunk(Pv, base4 + (size_t)c * 7, bf, a2);
        for (int r = (nch << 2) + tid; r < rows_here; r += 256) {
            float p[KCOLS];
            const float* row = P + (size_t)(row0 + r) * KCOLS;
            for (int j = 0; j < KCOLS; ++j) p[j] = row[j];
            float q[KCOLS], sq;
            softmax10(p, q, sq);
            float dot = bf[KCOLS];
            for (int j = 0; j < KCOLS; ++j) dot = fmaf(q[j], bf[j], dot);
            const float rr = rcp_nr(dot);
            for (int j = 0; j < KCOLS; ++j) a2[j] = fmaf(q[j], rr, a2[j]);
            a2[KCOLS] += rr;
        }

#pragma unroll
        for (int j = 0; j < MCOLS; ++j) {
            float v = a2[j];
#pragma unroll
            for (int off = 32; off > 0; off >>= 1) v += __shfl_down(v, off, 64);
            if (lane == 0) wred[wv][j] = (double)v;
        }
        __syncthreads();
        if (tid < MCOLS)
            partials[((size_t)par * nb + bx) * MCOLS + tid] =
                wred[0][tid] + wred[1][tid] + wred[2][tid] + wred[3][tid];
        grid.sync();
    }

    // ---------------- final pass: exact f32 q from P, write plan -----------
    float bfin[MCOLS], bpf[MCOLS];
#pragma unroll
    for (int j = 0; j < MCOLS; ++j) { bfin[j] = (float)b[j]; bpf[j] = (float)bprev[j]; }

    float4* Ov = (float4*)out;
    for (int c = tid; c < nch; c += 256)
        final_chunk(Pv, Ov, base4 + (size_t)c * 7, bpf, bfin);
    for (int r = (nch << 2) + tid; r < rows_here; r += 256) {
        float p[KCOLS];
        const float* row = P + (size_t)(row0 + r) * KCOLS;
        for (int j = 0; j < KCOLS; ++j) p[j] = row[j];
        float q[KCOLS], sq;
        softmax10(p, q, sq);
        float dot = bpf[KCOLS];
        for (int j = 0; j < KCOLS; ++j) dot = fmaf(q[j], bpf[j], dot);
        const float rr = rcp_nr(dot);
        float* orow = out + (size_t)(row0 + r) * KCOLS;
        for (int j = 0; j < KCOLS; ++j) orow[j] = q[j] * bfin[j] * rr;
    }
}

extern "C" void kernel_launch(void* const* d_in, const int* in_sizes, int n_in,
                              void* d_out, int out_size, void* d_ws, size_t ws_size,
                              hipStream_t stream) {
    (void)n_in; (void)out_size;
    const float* P = (const float*)d_in[0];
    float* out = (float*)d_out;
    const int n = in_sizes[0] / KCOLS;
    double* partials = (double*)d_ws;

    int dev = 0;
    hipGetDevice(&dev);
    int cus = 0;
    hipDeviceGetAttribute(&cus, hipDeviceAttributeMultiprocessorCount, dev);
    if (cus <= 0) cus = 256;
    int maxb = 0;
    if (hipOccupancyMaxActiveBlocksPerMultiprocessor(&maxb, sinkhorn_v3, 256, 0) != hipSuccess || maxb < 1)
        maxb = 1;

    long long cap = (long long)maxb * cus;   // cooperative co-residency limit
    int nb = NB_PREF;
    if (nb > cap) nb = (int)cap;
    while (nb > 64 && (size_t)(2ull * nb * MCOLS * sizeof(double)) > ws_size) nb >>= 1;
    if (nb < 1) nb = 1;
    int rpb = (((n + nb - 1) / nb) + 3) & ~3;  // multiple of 4 keeps float4 alignment

    void* args[] = {(void*)&P, (void*)&out, (void*)&partials, (void*)&n,
                    (void*)&nb, (void*)&rpb};
    hipLaunchCooperativeKernel((void*)sinkhorn_v3, dim3(nb), dim3(256),
                               args, 0, stream);
}

// Round 4
// 1656.940 us; speedup vs baseline: 2.0085x; 1.2067x over previous
//
#include <hip/hip_runtime.h>

#define KCOLS 7
#define MCOLS 8
#define LDSCH 768     // 4-row chunks cached in LDS  (3072 rows, 48 KB)
#define CACHECH 1024  // total cached chunks incl. 256 register chunks (4096 rows)
#define NB_PREF 512

// 64-byte slot: one block's iteration partial + release tag
struct __align__(64) Slot {
    float d[MCOLS];       // 32 B
    unsigned int tag;     // monotone iteration tag (poison 0xAAAAAAAA never matches)
    unsigned int pad[7];  // -> 64 B
};

// round-to-nearest-even pack of two f32 into bf16x2 (lo=a, hi=b)
__device__ __forceinline__ uint32_t pk_bf16(float a, float b) {
    uint32_t ua = __float_as_uint(a), ub = __float_as_uint(b);
    ua += 0x7FFFu + ((ua >> 16) & 1u);
    ub += 0x7FFFu + ((ub >> 16) & 1u);
    return (ua >> 16) | (ub & 0xFFFF0000u);
}
__device__ __forceinline__ void unp(uint32_t u, float& lo, float& hi) {
    lo = __uint_as_float(u << 16);
    hi = __uint_as_float(u & 0xFFFF0000u);
}
__device__ __forceinline__ float rcp_nr(float d) {
    float r = __builtin_amdgcn_rcpf(d);
    return fmaf(fmaf(-d, r, 1.0f), r, r);  // one Newton step -> ~1e-7 rel
}
// q = softmax(p)^10 (f32), sq = sum q
__device__ __forceinline__ void softmax10(const float* p, float* q, float& sq) {
    float mx = p[0];
#pragma unroll
    for (int j = 1; j < KCOLS; ++j) mx = fmaxf(mx, p[j]);
    float s = 0.0f;
#pragma unroll
    for (int j = 0; j < KCOLS; ++j) s += __expf(p[j] - mx);
    const float ls10 = 10.0f * __logf(s);
    sq = 0.0f;
#pragma unroll
    for (int j = 0; j < KCOLS; ++j) {
        q[j] = __expf(fmaf(10.0f, p[j] - mx, -ls10));
        sq += q[j];
    }
}

// setup: one 4-row chunk -> acc (b0 = 1/8 everywhere) + packed bf16 rows
__device__ __forceinline__ void setup_chunk(const float4* Pv, size_t f4base,
                                            float* acc, uint4* qq) {
    union { float4 v4[7]; float f[28]; } u;
#pragma unroll
    for (int i = 0; i < 7; ++i) u.v4[i] = Pv[f4base + i];
#pragma unroll
    for (int k = 0; k < 4; ++k) {
        float q[KCOLS], sq;
        softmax10(u.f + k * 7, q, sq);
        qq[k] = make_uint4(pk_bf16(q[0], q[1]), pk_bf16(q[2], q[3]),
                           pk_bf16(q[4], q[5]), pk_bf16(q[6], 1.0f));
        const float rr = rcp_nr(0.125f * (sq + 1.0f));
#pragma unroll
        for (int j = 0; j < KCOLS; ++j) acc[j] = fmaf(q[j], rr, acc[j]);
        acc[KCOLS] += rr;
    }
}

// iteration contribution of one cached (bf16-packed) row
__device__ __forceinline__ void cached_row(uint4 u, const float* bf, float* acc) {
    float f0, f1, f2, f3, f4, f5, f6, f7;
    unp(u.x, f0, f1); unp(u.y, f2, f3); unp(u.z, f4, f5); unp(u.w, f6, f7);
    float dot = f0 * bf[0];
    dot = fmaf(f1, bf[1], dot); dot = fmaf(f2, bf[2], dot);
    dot = fmaf(f3, bf[3], dot); dot = fmaf(f4, bf[4], dot);
    dot = fmaf(f5, bf[5], dot); dot = fmaf(f6, bf[6], dot);
    dot = fmaf(f7, bf[7], dot);
    const float rr = rcp_nr(dot);
    acc[0] = fmaf(f0, rr, acc[0]); acc[1] = fmaf(f1, rr, acc[1]);
    acc[2] = fmaf(f2, rr, acc[2]); acc[3] = fmaf(f3, rr, acc[3]);
    acc[4] = fmaf(f4, rr, acc[4]); acc[5] = fmaf(f5, rr, acc[5]);
    acc[6] = fmaf(f6, rr, acc[6]); acc[7] = fmaf(f7, rr, acc[7]);
}

// iteration contribution of one streamed chunk (recompute q from P)
__device__ __forceinline__ void stream_chunk(const float4* Pv, size_t f4base,
                                             const float* bf, float* acc) {
    union { float4 v4[7]; float f[28]; } u;
#pragma unroll
    for (int i = 0; i < 7; ++i) u.v4[i] = Pv[f4base + i];
#pragma unroll
    for (int k = 0; k < 4; ++k) {
        float q[KCOLS], sq;
        softmax10(u.f + k * 7, q, sq);
        float dot = bf[KCOLS];
#pragma unroll
        for (int j = 0; j < KCOLS; ++j) dot = fmaf(q[j], bf[j], dot);
        const float rr = rcp_nr(dot);
#pragma unroll
        for (int j = 0; j < KCOLS; ++j) acc[j] = fmaf(q[j], rr, acc[j]);
        acc[KCOLS] += rr;
    }
}

// final: one chunk -> plan
__device__ __forceinline__ void final_chunk(const float4* Pv, float4* Ov, size_t f4base,
                                            const float* bpf, const float* bfin) {
    union { float4 v4[7]; float f[28]; } u;
    union { float4 v4[7]; float f[28]; } o;
#pragma unroll
    for (int i = 0; i < 7; ++i) u.v4[i] = Pv[f4base + i];
#pragma unroll
    for (int k = 0; k < 4; ++k) {
        float q[KCOLS], sq;
        softmax10(u.f + k * 7, q, sq);
        float dot = bpf[KCOLS];
#pragma unroll
        for (int j = 0; j < KCOLS; ++j) dot = fmaf(q[j], bpf[j], dot);
        const float rr = rcp_nr(dot);
#pragma unroll
        for (int j = 0; j < KCOLS; ++j) o.f[k * 7 + j] = q[j] * bfin[j] * rr;
    }
#pragma unroll
    for (int i = 0; i < 7; ++i) Ov[f4base + i] = o.v4[i];
}

// Persistent cooperative Sinkhorn, NO grid.sync: blocks exchange per-iteration
// partials through tagged 64-B slots with agent-scope release/acquire atomics.
// Every block reduces all nb slots in a fixed deterministic order -> bit-identical
// b vector and convergence decision in every block.
__global__ __launch_bounds__(256, 2)
void sinkhorn_v4(const float* __restrict__ P, float* __restrict__ out,
                 Slot* __restrict__ slots, int n, int nb, int rpb) {
    const int tid = threadIdx.x, bx = blockIdx.x;
    const int lane = tid & 63, wv = tid >> 6;
    const double inv_n = 1.0 / (double)n;
    const double fi = 1.0 / 1.1;  // GAMMA/(GAMMA+EPSILON)
    const double Pb[MCOLS] = {0.17, 0.14, 0.15, 0.12, 0.05, 0.13, 0.24, 0.0};

    __shared__ uint4 qsh[LDSCH * 4];     // 48 KB
    __shared__ double wred[4][MCOLS];
    __shared__ double bn_sh[MCOLS];

    const int row0 = bx * rpb;           // rpb is a multiple of 4
    int rows_here = n - row0;
    if (rows_here > rpb) rows_here = rpb;
    if (rows_here < 0) rows_here = 0;
    const int nch = rows_here >> 2;                       // full 4-row chunks
    const int nlds = (nch < LDSCH) ? nch : LDSCH;
    const int ncached = (nch < CACHECH) ? nch : CACHECH;
    const size_t base4 = (size_t)(row0 >> 2) * 7;         // float4 index
    const float4* Pv = (const float4*)P;

    uint4 rq[4];                          // register-cached chunk (4 rows)
    const int crg = LDSCH + tid;
    const bool have_reg = (crg < ncached);

    // ---------------- setup pass: read P, cache q, fold iteration 1 --------
    float acc[MCOLS];
#pragma unroll
    for (int j = 0; j < MCOLS; ++j) acc[j] = 0.0f;

#pragma unroll
    for (int jj = 0; jj < 3; ++jj) {
        const int c = tid + 256 * jj;
        if (c < nlds) {
            uint4 qq[4];
            setup_chunk(Pv, base4 + (size_t)c * 7, acc, qq);
#pragma unroll
            for (int k = 0; k < 4; ++k) qsh[c * 4 + k] = qq[k];
        }
    }
    if (have_reg) setup_chunk(Pv, base4 + (size_t)crg * 7, acc, rq);
    for (int c = CACHECH + tid; c < nch; c += 256) {
        uint4 qq[4];
        setup_chunk(Pv, base4 + (size_t)c * 7, acc, qq);  // acc only
    }
    for (int r = (nch << 2) + tid; r < rows_here; r += 256) {  // scalar tail
        float p[KCOLS];
        const float* row = P + (size_t)(row0 + r) * KCOLS;
        for (int j = 0; j < KCOLS; ++j) p[j] = row[j];
        float q[KCOLS], sq;
        softmax10(p, q, sq);
        const float rr = rcp_nr(0.125f * (sq + 1.0f));
        for (int j = 0; j < KCOLS; ++j) acc[j] = fmaf(q[j], rr, acc[j]);
        acc[KCOLS] += rr;
    }

    // block reduce -> publish slot (parity 0, tag 1)
#pragma unroll
    for (int j = 0; j < MCOLS; ++j) {
        float v = acc[j];
#pragma unroll
        for (int off = 32; off > 0; off >>= 1) v += __shfl_down(v, off, 64);
        if (lane == 0) wred[wv][j] = (double)v;
    }
    __syncthreads();
    {
        Slot* my = slots + bx;  // parity 0
        if (tid < MCOLS) {
            const double v = wred[0][tid] + wred[1][tid] + wred[2][tid] + wred[3][tid];
            __hip_atomic_store(&my->d[tid], (float)v, __ATOMIC_RELAXED,
                               __HIP_MEMORY_SCOPE_AGENT);
        }
        __syncthreads();
        if (tid == 0)
            __hip_atomic_store(&my->tag, 1u, __ATOMIC_RELEASE,
                               __HIP_MEMORY_SCOPE_AGENT);
    }

    // ---------------- Sinkhorn loop (barrier-free) -------------------------
    double b[MCOLS], bprev[MCOLS];
#pragma unroll
    for (int j = 0; j < MCOLS; ++j) { b[j] = 0.125; bprev[j] = 0.125; }
    float bf[MCOLS];

    for (int it = 1; it <= 50; ++it) {
        // fused wait+reduce of iteration-it partials (parity (it-1)&1, tag it)
        const Slot* cur = slots + (size_t)((it - 1) & 1) * nb;
        const unsigned want = (unsigned)it;
        double c8[MCOLS];
#pragma unroll
        for (int j = 0; j < MCOLS; ++j) c8[j] = 0.0;
        for (int s = tid; s < nb; s += 256) {      // fixed order per thread
            const Slot* sp = cur + s;
            while (__hip_atomic_load(&sp->tag, __ATOMIC_ACQUIRE,
                                     __HIP_MEMORY_SCOPE_AGENT) != want)
                __builtin_amdgcn_s_sleep(1);
#pragma unroll
            for (int j = 0; j < MCOLS; ++j)
                c8[j] += (double)__hip_atomic_load(&sp->d[j], __ATOMIC_RELAXED,
                                                   __HIP_MEMORY_SCOPE_AGENT);
        }
#pragma unroll
        for (int j = 0; j < MCOLS; ++j) {          // f64 wave reduce, fixed tree
            double v = c8[j];
#pragma unroll
            for (int off = 32; off > 0; off >>= 1) v += __shfl_down(v, off, 64);
            if (lane == 0) wred[wv][j] = v;
        }
        __syncthreads();
        if (tid < MCOLS) {
            double c = wred[0][tid] + wred[1][tid] + wred[2][tid] + wred[3][tid];
            c *= inv_n;
            bn_sh[tid] = (tid < KCOLS) ? pow(Pb[tid] / c, fi) : 0.0;
        }
        __syncthreads();

        double err2 = 0.0;
#pragma unroll
        for (int j = 0; j < MCOLS; ++j) {
            const double bn = bn_sh[j];
            const double d = bn - b[j];
            err2 += d * d;
            bprev[j] = b[j];
            b[j] = bn;
            bf[j] = (float)bn;
        }
        if (err2 <= 1e-12 || it == 50) break;  // identical decision in all blocks

        // pass with new b: cached LDS rows + register rows + streamed rows
        float a2[MCOLS];
#pragma unroll
        for (int j = 0; j < MCOLS; ++j) a2[j] = 0.0f;
#pragma unroll
        for (int jj = 0; jj < 12; ++jj) {
            const int r = tid + 256 * jj;
            if (r < nlds * 4) cached_row(qsh[r], bf, a2);
        }
        if (have_reg) {
#pragma unroll
            for (int k = 0; k < 4; ++k) cached_row(rq[k], bf, a2);
        }
        for (int c = CACHECH + tid; c < nch; c += 256)
            stream_chunk(Pv, base4 + (size_t)c * 7, bf, a2);
        for (int r = (nch << 2) + tid; r < rows_here; r += 256) {
            float p[KCOLS];
            const float* row = P + (size_t)(row0 + r) * KCOLS;
            for (int j = 0; j < KCOLS; ++j) p[j] = row[j];
            float q[KCOLS], sq;
            softmax10(p, q, sq);
            float dot = bf[KCOLS];
            for (int j = 0; j < KCOLS; ++j) dot = fmaf(q[j], bf[j], dot);
            const float rr = rcp_nr(dot);
            for (int j = 0; j < KCOLS; ++j) a2[j] = fmaf(q[j], rr, a2[j]);
            a2[KCOLS] += rr;
        }

#pragma unroll
        for (int j = 0; j < MCOLS; ++j) {
            float v = a2[j];
#pragma unroll
            for (int off = 32; off > 0; off >>= 1) v += __shfl_down(v, off, 64);
            if (lane == 0) wred[wv][j] = (double)v;
        }
        __syncthreads();
        {
            Slot* my = slots + (size_t)(it & 1) * nb + bx;
            if (tid < MCOLS) {
                const double v = wred[0][tid] + wred[1][tid] + wred[2][tid] + wred[3][tid];
                __hip_atomic_store(&my->d[tid], (float)v, __ATOMIC_RELAXED,
                                   __HIP_MEMORY_SCOPE_AGENT);
            }
            __syncthreads();
            if (tid == 0)
                __hip_atomic_store(&my->tag, (unsigned)(it + 1), __ATOMIC_RELEASE,
                                   __HIP_MEMORY_SCOPE_AGENT);
        }
    }

    // ---------------- final pass: exact f32 q from P, write plan -----------
    float bfin[MCOLS], bpf[MCOLS];
#pragma unroll
    for (int j = 0; j < MCOLS; ++j) { bfin[j] = (float)b[j]; bpf[j] = (float)bprev[j]; }

    float4* Ov = (float4*)out;
    for (int c = tid; c < nch; c += 256)
        final_chunk(Pv, Ov, base4 + (size_t)c * 7, bpf, bfin);
    for (int r = (nch << 2) + tid; r < rows_here; r += 256) {
        float p[KCOLS];
        const float* row = P + (size_t)(row0 + r) * KCOLS;
        for (int j = 0; j < KCOLS; ++j) p[j] = row[j];
        float q[KCOLS], sq;
        softmax10(p, q, sq);
        float dot = bpf[KCOLS];
        for (int j = 0; j < KCOLS; ++j) dot = fmaf(q[j], bpf[j], dot);
        const float rr = rcp_nr(dot);
        float* orow = out + (size_t)(row0 + r) * KCOLS;
        for (int j = 0; j < KCOLS; ++j) orow[j] = q[j] * bfin[j] * rr;
    }
}

extern "C" void kernel_launch(void* const* d_in, const int* in_sizes, int n_in,
                              void* d_out, int out_size, void* d_ws, size_t ws_size,
                              hipStream_t stream) {
    (void)n_in; (void)out_size;
    const float* P = (const float*)d_in[0];
    float* out = (float*)d_out;
    const int n = in_sizes[0] / KCOLS;
    Slot* slots = (Slot*)d_ws;

    int dev = 0;
    hipGetDevice(&dev);
    int cus = 0;
    hipDeviceGetAttribute(&cus, hipDeviceAttributeMultiprocessorCount, dev);
    if (cus <= 0) cus = 256;
    int maxb = 0;
    if (hipOccupancyMaxActiveBlocksPerMultiprocessor(&maxb, sinkhorn_v4, 256, 0) != hipSuccess || maxb < 1)
        maxb = 1;

    long long cap = (long long)maxb * cus;   // cooperative co-residency limit
    int nb = NB_PREF;
    if (nb > cap) nb = (int)cap;
    while (nb > 64 && (size_t)(2ull * nb * sizeof(Slot)) > ws_size) nb >>= 1;
    if (nb < 1) nb = 1;
    int rpb = (((n + nb - 1) / nb) + 3) & ~3;  // multiple of 4 keeps float4 alignment

    void* args[] = {(void*)&P, (void*)&out, (void*)&slots, (void*)&n,
                    (void*)&nb, (void*)&rpb};
    hipLaunchCooperativeKernel((void*)sinkhorn_v4, dim3(nb), dim3(256),
                               args, 0, stream);
}

// Round 5
// 1050.449 us; speedup vs baseline: 3.1682x; 1.5774x over previous
//
#include <hip/hip_runtime.h>

#define KCOLS 7
#define MCOLS 8
#define LDSCH 768     // 4-row chunks cached in LDS  (3072 rows, 48 KB)
#define CACHECH 1024  // total cached chunks incl. 256 register chunks (4096 rows)
#define NB_PREF 512
#define TAG_MASK 0x7fffffffu
#define STOP_BIT 0x80000000u

// per-block partial: one 64-B line (data + tag). Poison 0xAAAAAAAA never
// matches a tag (tags are 1..51, optionally with STOP_BIT, written monotone).
struct __align__(64) PSlot {
    float d[MCOLS];       // 32 B
    unsigned int tag;
    unsigned int pad[7];  // -> 64 B
};
// leader broadcast: b (f64 x8) + tag|stop, one 128-B line, double-buffered
struct __align__(128) BSlot {
    double b[MCOLS];      // 64 B
    unsigned int tag;
    unsigned int pad[15]; // -> 128 B
};

// round-to-nearest-even pack of two f32 into bf16x2 (lo=a, hi=b)
__device__ __forceinline__ uint32_t pk_bf16(float a, float b) {
    uint32_t ua = __float_as_uint(a), ub = __float_as_uint(b);
    ua += 0x7FFFu + ((ua >> 16) & 1u);
    ub += 0x7FFFu + ((ub >> 16) & 1u);
    return (ua >> 16) | (ub & 0xFFFF0000u);
}
__device__ __forceinline__ void unp(uint32_t u, float& lo, float& hi) {
    lo = __uint_as_float(u << 16);
    hi = __uint_as_float(u & 0xFFFF0000u);
}
__device__ __forceinline__ float rcp_nr(float d) {
    float r = __builtin_amdgcn_rcpf(d);
    return fmaf(fmaf(-d, r, 1.0f), r, r);  // one Newton step -> ~1e-7 rel
}
// q = softmax(p)^10 (f32), sq = sum q
__device__ __forceinline__ void softmax10(const float* p, float* q, float& sq) {
    float mx = p[0];
#pragma unroll
    for (int j = 1; j < KCOLS; ++j) mx = fmaxf(mx, p[j]);
    float s = 0.0f;
#pragma unroll
    for (int j = 0; j < KCOLS; ++j) s += __expf(p[j] - mx);
    const float ls10 = 10.0f * __logf(s);
    sq = 0.0f;
#pragma unroll
    for (int j = 0; j < KCOLS; ++j) {
        q[j] = __expf(fmaf(10.0f, p[j] - mx, -ls10));
        sq += q[j];
    }
}

__device__ __forceinline__ void setup_chunk(const float4* Pv, size_t f4base,
                                            float* acc, uint4* qq) {
    union { float4 v4[7]; float f[28]; } u;
#pragma unroll
    for (int i = 0; i < 7; ++i) u.v4[i] = Pv[f4base + i];
#pragma unroll
    for (int k = 0; k < 4; ++k) {
        float q[KCOLS], sq;
        softmax10(u.f + k * 7, q, sq);
        qq[k] = make_uint4(pk_bf16(q[0], q[1]), pk_bf16(q[2], q[3]),
                           pk_bf16(q[4], q[5]), pk_bf16(q[6], 1.0f));
        const float rr = rcp_nr(0.125f * (sq + 1.0f));   // fold iter 1, b0=1/8
#pragma unroll
        for (int j = 0; j < KCOLS; ++j) acc[j] = fmaf(q[j], rr, acc[j]);
        acc[KCOLS] += rr;
    }
}

__device__ __forceinline__ void cached_row(uint4 u, const float* bf, float* acc) {
    float f0, f1, f2, f3, f4, f5, f6, f7;
    unp(u.x, f0, f1); unp(u.y, f2, f3); unp(u.z, f4, f5); unp(u.w, f6, f7);
    float dot = f0 * bf[0];
    dot = fmaf(f1, bf[1], dot); dot = fmaf(f2, bf[2], dot);
    dot = fmaf(f3, bf[3], dot); dot = fmaf(f4, bf[4], dot);
    dot = fmaf(f5, bf[5], dot); dot = fmaf(f6, bf[6], dot);
    dot = fmaf(f7, bf[7], dot);
    const float rr = rcp_nr(dot);
    acc[0] = fmaf(f0, rr, acc[0]); acc[1] = fmaf(f1, rr, acc[1]);
    acc[2] = fmaf(f2, rr, acc[2]); acc[3] = fmaf(f3, rr, acc[3]);
    acc[4] = fmaf(f4, rr, acc[4]); acc[5] = fmaf(f5, rr, acc[5]);
    acc[6] = fmaf(f6, rr, acc[6]); acc[7] = fmaf(f7, rr, acc[7]);
}

__device__ __forceinline__ void stream_chunk(const float4* Pv, size_t f4base,
                                             const float* bf, float* acc) {
    union { float4 v4[7]; float f[28]; } u;
#pragma unroll
    for (int i = 0; i < 7; ++i) u.v4[i] = Pv[f4base + i];
#pragma unroll
    for (int k = 0; k < 4; ++k) {
        float q[KCOLS], sq;
        softmax10(u.f + k * 7, q, sq);
        float dot = bf[KCOLS];
#pragma unroll
        for (int j = 0; j < KCOLS; ++j) dot = fmaf(q[j], bf[j], dot);
        const float rr = rcp_nr(dot);
#pragma unroll
        for (int j = 0; j < KCOLS; ++j) acc[j] = fmaf(q[j], rr, acc[j]);
        acc[KCOLS] += rr;
    }
}

__device__ __forceinline__ void final_chunk(const float4* Pv, float4* Ov, size_t f4base,
                                            const float* bpf, const float* bfin) {
    union { float4 v4[7]; float f[28]; } u;
    union { float4 v4[7]; float f[28]; } o;
#pragma unroll
    for (int i = 0; i < 7; ++i) u.v4[i] = Pv[f4base + i];
#pragma unroll
    for (int k = 0; k < 4; ++k) {
        float q[KCOLS], sq;
        softmax10(u.f + k * 7, q, sq);
        float dot = bpf[KCOLS];
#pragma unroll
        for (int j = 0; j < KCOLS; ++j) dot = fmaf(q[j], bpf[j], dot);
        const float rr = rcp_nr(dot);
#pragma unroll
        for (int j = 0; j < KCOLS; ++j) o.f[k * 7 + j] = q[j] * bfin[j] * rr;
    }
#pragma unroll
    for (int i = 0; i < 7; ++i) Ov[f4base + i] = o.v4[i];
}

// Persistent cooperative Sinkhorn, leader-broadcast sync topology:
// blocks publish partials (release); block 0 alone reduces them (relaxed polls
// + one acquire fence), computes b, and broadcasts it on ONE line; other
// blocks poll that line with a single thread. No grid barrier, no per-poll
// cache-maintenance storm.
__global__ __launch_bounds__(256, 2)
void sinkhorn_v5(const float* __restrict__ P, float* __restrict__ out,
                 PSlot* __restrict__ pslots, BSlot* __restrict__ bslots,
                 int n, int nb, int rpb) {
    const int tid = threadIdx.x, bx = blockIdx.x;
    const int lane = tid & 63, wv = tid >> 6;
    const double inv_n = 1.0 / (double)n;
    const double fi = 1.0 / 1.1;  // GAMMA/(GAMMA+EPSILON)
    const double Pb[MCOLS] = {0.17, 0.14, 0.15, 0.12, 0.05, 0.13, 0.24, 0.0};

    __shared__ uint4 qsh[LDSCH * 4];     // 48 KB
    __shared__ double wred[4][MCOLS];
    __shared__ double bn_sh[MCOLS];
    __shared__ int stop_sh;

    const int row0 = bx * rpb;           // rpb is a multiple of 4
    int rows_here = n - row0;
    if (rows_here > rpb) rows_here = rpb;
    if (rows_here < 0) rows_here = 0;
    const int nch = rows_here >> 2;
    const int nlds = (nch < LDSCH) ? nch : LDSCH;
    const int ncached = (nch < CACHECH) ? nch : CACHECH;
    const size_t base4 = (size_t)(row0 >> 2) * 7;
    const float4* Pv = (const float4*)P;

    uint4 rq[4];
    const int crg = LDSCH + tid;
    const bool have_reg = (crg < ncached);

    // ---------------- setup pass: read P, cache q, fold iteration 1 --------
    float acc[MCOLS];
#pragma unroll
    for (int j = 0; j < MCOLS; ++j) acc[j] = 0.0f;

#pragma unroll
    for (int jj = 0; jj < 3; ++jj) {
        const int c = tid + 256 * jj;
        if (c < nlds) {
            uint4 qq[4];
            setup_chunk(Pv, base4 + (size_t)c * 7, acc, qq);
#pragma unroll
            for (int k = 0; k < 4; ++k) qsh[c * 4 + k] = qq[k];
        }
    }
    if (have_reg) setup_chunk(Pv, base4 + (size_t)crg * 7, acc, rq);
    for (int c = CACHECH + tid; c < nch; c += 256) {
        uint4 qq[4];
        setup_chunk(Pv, base4 + (size_t)c * 7, acc, qq);
    }
    for (int r = (nch << 2) + tid; r < rows_here; r += 256) {
        float p[KCOLS];
        const float* row = P + (size_t)(row0 + r) * KCOLS;
        for (int j = 0; j < KCOLS; ++j) p[j] = row[j];
        float q[KCOLS], sq;
        softmax10(p, q, sq);
        const float rr = rcp_nr(0.125f * (sq + 1.0f));
        for (int j = 0; j < KCOLS; ++j) acc[j] = fmaf(q[j], rr, acc[j]);
        acc[KCOLS] += rr;
    }

    // block reduce -> publish partial (parity 0, tag 1)
#pragma unroll
    for (int j = 0; j < MCOLS; ++j) {
        float v = acc[j];
#pragma unroll
        for (int off = 32; off > 0; off >>= 1) v += __shfl_down(v, off, 64);
        if (lane == 0) wred[wv][j] = (double)v;
    }
    __syncthreads();
    {
        PSlot* my = pslots + bx;
        if (tid < MCOLS)
            __hip_atomic_store(&my->d[tid],
                (float)(wred[0][tid] + wred[1][tid] + wred[2][tid] + wred[3][tid]),
                __ATOMIC_RELAXED, __HIP_MEMORY_SCOPE_AGENT);
        __syncthreads();
        if (tid == 0) {
            __builtin_amdgcn_fence(__ATOMIC_RELEASE, "agent");
            __hip_atomic_store(&my->tag, 1u, __ATOMIC_RELAXED,
                               __HIP_MEMORY_SCOPE_AGENT);
        }
    }

    // ---------------- Sinkhorn loop ---------------------------------------
    double b[MCOLS], bprev[MCOLS];
#pragma unroll
    for (int j = 0; j < MCOLS; ++j) { b[j] = 0.125; bprev[j] = 0.125; }
    float bf[MCOLS];

    for (int it = 1; it <= 50; ++it) {
        const int p = (it - 1) & 1;
        int stop;
        if (bx == 0) {
            // -------- leader: reduce partials tagged it, publish b ---------
            const PSlot* cur = pslots + (size_t)p * nb;
            for (int s = tid; s < nb; s += 256) {
                const PSlot* sp = cur + s;
                while (__hip_atomic_load(&sp->tag, __ATOMIC_RELAXED,
                                         __HIP_MEMORY_SCOPE_AGENT) != (unsigned)it)
                    __builtin_amdgcn_s_sleep(1);
            }
            __builtin_amdgcn_fence(__ATOMIC_ACQUIRE, "agent");
            double c8[MCOLS];
#pragma unroll
            for (int j = 0; j < MCOLS; ++j) c8[j] = 0.0;
            for (int s = tid; s < nb; s += 256) {
                const PSlot* sp = cur + s;
#pragma unroll
                for (int j = 0; j < MCOLS; ++j)
                    c8[j] += (double)__hip_atomic_load(&sp->d[j], __ATOMIC_RELAXED,
                                                       __HIP_MEMORY_SCOPE_AGENT);
            }
#pragma unroll
            for (int j = 0; j < MCOLS; ++j) {
                double v = c8[j];
#pragma unroll
                for (int off = 32; off > 0; off >>= 1) v += __shfl_down(v, off, 64);
                if (lane == 0) wred[wv][j] = v;
            }
            __syncthreads();
            if (tid < MCOLS) {
                double c = wred[0][tid] + wred[1][tid] + wred[2][tid] + wred[3][tid];
                c *= inv_n;
                bn_sh[tid] = (tid < KCOLS) ? pow(Pb[tid] / c, fi) : 0.0;
            }
            __syncthreads();
            double err2 = 0.0;
#pragma unroll
            for (int j = 0; j < MCOLS; ++j) {
                const double d = bn_sh[j] - b[j];
                err2 += d * d;
            }
            stop = (err2 <= 1e-12 || it == 50) ? 1 : 0;
            if (tid == 0) {
                BSlot* bs = bslots + p;
#pragma unroll
                for (int j = 0; j < MCOLS; ++j)
                    __hip_atomic_store(&bs->b[j], bn_sh[j], __ATOMIC_RELAXED,
                                       __HIP_MEMORY_SCOPE_AGENT);
                __builtin_amdgcn_fence(__ATOMIC_RELEASE, "agent");
                __hip_atomic_store(&bs->tag,
                                   (unsigned)it | (stop ? STOP_BIT : 0u),
                                   __ATOMIC_RELAXED, __HIP_MEMORY_SCOPE_AGENT);
            }
        } else {
            // -------- follower: single-thread poll of the broadcast line ---
            if (tid == 0) {
                const BSlot* bs = bslots + p;
                unsigned t;
                while (((t = __hip_atomic_load(&bs->tag, __ATOMIC_RELAXED,
                                               __HIP_MEMORY_SCOPE_AGENT))
                        & TAG_MASK) != (unsigned)it)
                    __builtin_amdgcn_s_sleep(4);
                __builtin_amdgcn_fence(__ATOMIC_ACQUIRE, "agent");
#pragma unroll
                for (int j = 0; j < MCOLS; ++j)
                    bn_sh[j] = __hip_atomic_load(&bs->b[j], __ATOMIC_RELAXED,
                                                 __HIP_MEMORY_SCOPE_AGENT);
                stop_sh = (int)(t >> 31);
            }
            __syncthreads();
            stop = stop_sh;
        }

#pragma unroll
        for (int j = 0; j < MCOLS; ++j) {
            bprev[j] = b[j];
            b[j] = bn_sh[j];
            bf[j] = (float)b[j];
        }
        if (stop) break;

        // -------- compute pass with new b ----------------------------------
        float a2[MCOLS];
#pragma unroll
        for (int j = 0; j < MCOLS; ++j) a2[j] = 0.0f;
#pragma unroll
        for (int jj = 0; jj < 12; ++jj) {
            const int r = tid + 256 * jj;
            if (r < nlds * 4) cached_row(qsh[r], bf, a2);
        }
        if (have_reg) {
#pragma unroll
            for (int k = 0; k < 4; ++k) cached_row(rq[k], bf, a2);
        }
        for (int c = CACHECH + tid; c < nch; c += 256)
            stream_chunk(Pv, base4 + (size_t)c * 7, bf, a2);
        for (int r = (nch << 2) + tid; r < rows_here; r += 256) {
            float p2[KCOLS];
            const float* row = P + (size_t)(row0 + r) * KCOLS;
            for (int j = 0; j < KCOLS; ++j) p2[j] = row[j];
            float q[KCOLS], sq;
            softmax10(p2, q, sq);
            float dot = bf[KCOLS];
            for (int j = 0; j < KCOLS; ++j) dot = fmaf(q[j], bf[j], dot);
            const float rr = rcp_nr(dot);
            for (int j = 0; j < KCOLS; ++j) a2[j] = fmaf(q[j], rr, a2[j]);
            a2[KCOLS] += rr;
        }

#pragma unroll
        for (int j = 0; j < MCOLS; ++j) {
            float v = a2[j];
#pragma unroll
            for (int off = 32; off > 0; off >>= 1) v += __shfl_down(v, off, 64);
            if (lane == 0) wred[wv][j] = (double)v;
        }
        __syncthreads();
        {
            PSlot* my = pslots + (size_t)(it & 1) * nb + bx;
            if (tid < MCOLS)
                __hip_atomic_store(&my->d[tid],
                    (float)(wred[0][tid] + wred[1][tid] + wred[2][tid] + wred[3][tid]),
                    __ATOMIC_RELAXED, __HIP_MEMORY_SCOPE_AGENT);
            __syncthreads();
            if (tid == 0) {
                __builtin_amdgcn_fence(__ATOMIC_RELEASE, "agent");
                __hip_atomic_store(&my->tag, (unsigned)(it + 1), __ATOMIC_RELAXED,
                                   __HIP_MEMORY_SCOPE_AGENT);
            }
        }
    }

    // ---------------- final pass: exact f32 q from P, write plan -----------
    float bfin[MCOLS], bpf[MCOLS];
#pragma unroll
    for (int j = 0; j < MCOLS; ++j) { bfin[j] = (float)b[j]; bpf[j] = (float)bprev[j]; }

    float4* Ov = (float4*)out;
    for (int c = tid; c < nch; c += 256)
        final_chunk(Pv, Ov, base4 + (size_t)c * 7, bpf, bfin);
    for (int r = (nch << 2) + tid; r < rows_here; r += 256) {
        float p[KCOLS];
        const float* row = P + (size_t)(row0 + r) * KCOLS;
        for (int j = 0; j < KCOLS; ++j) p[j] = row[j];
        float q[KCOLS], sq;
        softmax10(p, q, sq);
        float dot = bpf[KCOLS];
        for (int j = 0; j < KCOLS; ++j) dot = fmaf(q[j], bpf[j], dot);
        const float rr = rcp_nr(dot);
        float* orow = out + (size_t)(row0 + r) * KCOLS;
        for (int j = 0; j < KCOLS; ++j) orow[j] = q[j] * bfin[j] * rr;
    }
}

extern "C" void kernel_launch(void* const* d_in, const int* in_sizes, int n_in,
                              void* d_out, int out_size, void* d_ws, size_t ws_size,
                              hipStream_t stream) {
    (void)n_in; (void)out_size;
    const float* P = (const float*)d_in[0];
    float* out = (float*)d_out;
    const int n = in_sizes[0] / KCOLS;

    int dev = 0;
    hipGetDevice(&dev);
    int cus = 0;
    hipDeviceGetAttribute(&cus, hipDeviceAttributeMultiprocessorCount, dev);
    if (cus <= 0) cus = 256;
    int maxb = 0;
    if (hipOccupancyMaxActiveBlocksPerMultiprocessor(&maxb, sinkhorn_v5, 256, 0) != hipSuccess || maxb < 1)
        maxb = 1;

    long long cap = (long long)maxb * cus;
    int nb = NB_PREF;
    if (nb > cap) nb = (int)cap;
    while (nb > 64 && (size_t)(2ull * nb * sizeof(PSlot) + 2 * sizeof(BSlot) + 128) > ws_size)
        nb >>= 1;
    if (nb < 1) nb = 1;
    nb &= ~1;                       // keep even so BSlot offset stays 128-aligned
    if (nb < 2) nb = 2;
    int rpb = (((n + nb - 1) / nb) + 3) & ~3;

    PSlot* pslots = (PSlot*)d_ws;
    BSlot* bslots = (BSlot*)((char*)d_ws + (size_t)2 * nb * sizeof(PSlot));

    void* args[] = {(void*)&P, (void*)&out, (void*)&pslots, (void*)&bslots,
                    (void*)&n, (void*)&nb, (void*)&rpb};
    hipLaunchCooperativeKernel((void*)sinkhorn_v5, dim3(nb), dim3(256),
                               args, 0, stream);
}

// Round 6
// 766.720 us; speedup vs baseline: 4.3406x; 1.3701x over previous
//
#include <hip/hip_runtime.h>

#define KCOLS 7
#define MCOLS 8
#define LDSCH 768     // 4-row chunks cached in LDS  (3072 rows, 48 KB)
#define CACHECH 1024  // total cached chunks incl. 256 register chunks (4096 rows)
#define NB_PREF 512
#define TAGM 0x7fffffffu

typedef unsigned long long u64;

// self-validating word: high32 = tag (| stop bit31 for broadcast), low32 = f32 bits
__device__ __forceinline__ u64 mkword(unsigned tag, float v) {
    return ((u64)tag << 32) | (u64)__float_as_uint(v);
}
__device__ __forceinline__ void st_rel(u64* p, u64 w) {
    __hip_atomic_store(p, w, __ATOMIC_RELAXED, __HIP_MEMORY_SCOPE_AGENT);
}
__device__ __forceinline__ u64 ld_rel(const u64* p) {
    return __hip_atomic_load(p, __ATOMIC_RELAXED, __HIP_MEMORY_SCOPE_AGENT);
}

// round-to-nearest-even pack of two f32 into bf16x2 (lo=a, hi=b)
__device__ __forceinline__ uint32_t pk_bf16(float a, float b) {
    uint32_t ua = __float_as_uint(a), ub = __float_as_uint(b);
    ua += 0x7FFFu + ((ua >> 16) & 1u);
    ub += 0x7FFFu + ((ub >> 16) & 1u);
    return (ua >> 16) | (ub & 0xFFFF0000u);
}
__device__ __forceinline__ void unp(uint32_t u, float& lo, float& hi) {
    lo = __uint_as_float(u << 16);
    hi = __uint_as_float(u & 0xFFFF0000u);
}
__device__ __forceinline__ float rcp_nr(float d) {
    float r = __builtin_amdgcn_rcpf(d);
    return fmaf(fmaf(-d, r, 1.0f), r, r);  // one Newton step -> ~1e-7 rel
}
// q = softmax(p)^10 (f32), sq = sum q
__device__ __forceinline__ void softmax10(const float* p, float* q, float& sq) {
    float mx = p[0];
#pragma unroll
    for (int j = 1; j < KCOLS; ++j) mx = fmaxf(mx, p[j]);
    float s = 0.0f;
#pragma unroll
    for (int j = 0; j < KCOLS; ++j) s += __expf(p[j] - mx);
    const float ls10 = 10.0f * __logf(s);
    sq = 0.0f;
#pragma unroll
    for (int j = 0; j < KCOLS; ++j) {
        q[j] = __expf(fmaf(10.0f, p[j] - mx, -ls10));
        sq += q[j];
    }
}

__device__ __forceinline__ void setup_chunk(const float4* Pv, size_t f4base,
                                            float* acc, uint4* qq) {
    union { float4 v4[7]; float f[28]; } u;
#pragma unroll
    for (int i = 0; i < 7; ++i) u.v4[i] = Pv[f4base + i];
#pragma unroll
    for (int k = 0; k < 4; ++k) {
        float q[KCOLS], sq;
        softmax10(u.f + k * 7, q, sq);
        qq[k] = make_uint4(pk_bf16(q[0], q[1]), pk_bf16(q[2], q[3]),
                           pk_bf16(q[4], q[5]), pk_bf16(q[6], 1.0f));
        const float rr = rcp_nr(0.125f * (sq + 1.0f));   // fold iter 1, b0=1/8
#pragma unroll
        for (int j = 0; j < KCOLS; ++j) acc[j] = fmaf(q[j], rr, acc[j]);
        acc[KCOLS] += rr;
    }
}

__device__ __forceinline__ void cached_row(uint4 u, const float* bf, float* acc) {
    float f0, f1, f2, f3, f4, f5, f6, f7;
    unp(u.x, f0, f1); unp(u.y, f2, f3); unp(u.z, f4, f5); unp(u.w, f6, f7);
    float dot = f0 * bf[0];
    dot = fmaf(f1, bf[1], dot); dot = fmaf(f2, bf[2], dot);
    dot = fmaf(f3, bf[3], dot); dot = fmaf(f4, bf[4], dot);
    dot = fmaf(f5, bf[5], dot); dot = fmaf(f6, bf[6], dot);
    dot = fmaf(f7, bf[7], dot);
    const float rr = rcp_nr(dot);
    acc[0] = fmaf(f0, rr, acc[0]); acc[1] = fmaf(f1, rr, acc[1]);
    acc[2] = fmaf(f2, rr, acc[2]); acc[3] = fmaf(f3, rr, acc[3]);
    acc[4] = fmaf(f4, rr, acc[4]); acc[5] = fmaf(f5, rr, acc[5]);
    acc[6] = fmaf(f6, rr, acc[6]); acc[7] = fmaf(f7, rr, acc[7]);
}

__device__ __forceinline__ void stream_chunk(const float4* Pv, size_t f4base,
                                             const float* bf, float* acc) {
    union { float4 v4[7]; float f[28]; } u;
#pragma unroll
    for (int i = 0; i < 7; ++i) u.v4[i] = Pv[f4base + i];
#pragma unroll
    for (int k = 0; k < 4; ++k) {
        float q[KCOLS], sq;
        softmax10(u.f + k * 7, q, sq);
        float dot = bf[KCOLS];
#pragma unroll
        for (int j = 0; j < KCOLS; ++j) dot = fmaf(q[j], bf[j], dot);
        const float rr = rcp_nr(dot);
#pragma unroll
        for (int j = 0; j < KCOLS; ++j) acc[j] = fmaf(q[j], rr, acc[j]);
        acc[KCOLS] += rr;
    }
}

__device__ __forceinline__ void final_chunk(const float4* Pv, float4* Ov, size_t f4base,
                                            const float* bpf, const float* bfin) {
    union { float4 v4[7]; float f[28]; } u;
    union { float4 v4[7]; float f[28]; } o;
#pragma unroll
    for (int i = 0; i < 7; ++i) u.v4[i] = Pv[f4base + i];
#pragma unroll
    for (int k = 0; k < 4; ++k) {
        float q[KCOLS], sq;
        softmax10(u.f + k * 7, q, sq);
        float dot = bpf[KCOLS];
#pragma unroll
        for (int j = 0; j < KCOLS; ++j) dot = fmaf(q[j], bpf[j], dot);
        const float rr = rcp_nr(dot);
#pragma unroll
        for (int j = 0; j < KCOLS; ++j) o.f[k * 7 + j] = q[j] * bfin[j] * rr;
    }
#pragma unroll
    for (int i = 0; i < 7; ++i) Ov[f4base + i] = o.v4[i];
}

// Persistent cooperative Sinkhorn, FENCE-FREE leader-broadcast sync:
// all cross-block words are (tag<<32 | f32) relaxed agent atomics -> no
// buffer_inv / wbl2 storms. Single buffer (no parity): the dependency chain
// leader-consumes(it) -> broadcast(it) -> workers-publish(it+1) makes
// overwrite-before-read impossible; tags are strictly monotone.
// pw[bx*8+j]: block partials.  bw[j]: leader's b broadcast (stop in bit63).
__global__ __launch_bounds__(256, 2)
void sinkhorn_v6(const float* __restrict__ P, float* __restrict__ out,
                 u64* __restrict__ pw, u64* __restrict__ bw,
                 int n, int nb, int rpb) {
    const int tid = threadIdx.x, bx = blockIdx.x;
    const int lane = tid & 63, wv = tid >> 6;
    const double inv_n = 1.0 / (double)n;
    const double fi = 1.0 / 1.1;  // GAMMA/(GAMMA+EPSILON)
    const double Pb[MCOLS] = {0.17, 0.14, 0.15, 0.12, 0.05, 0.13, 0.24, 0.0};

    __shared__ uint4 qsh[LDSCH * 4];     // 48 KB
    __shared__ double wred[4][MCOLS];
    __shared__ double bn_sh[MCOLS];
    __shared__ float bf_sh[MCOLS];
    __shared__ int stop_sh;

    const int row0 = bx * rpb;           // rpb multiple of 4
    int rows_here = n - row0;
    if (rows_here > rpb) rows_here = rpb;
    if (rows_here < 0) rows_here = 0;
    const int nch = rows_here >> 2;
    const int nlds = (nch < LDSCH) ? nch : LDSCH;
    const int ncached = (nch < CACHECH) ? nch : CACHECH;
    const size_t base4 = (size_t)(row0 >> 2) * 7;
    const float4* Pv = (const float4*)P;

    uint4 rq[4];
    const int crg = LDSCH + tid;
    const bool have_reg = (crg < ncached);

    // ---------------- setup pass: read P, cache q, fold iteration 1 --------
    float acc[MCOLS];
#pragma unroll
    for (int j = 0; j < MCOLS; ++j) acc[j] = 0.0f;

#pragma unroll
    for (int jj = 0; jj < 3; ++jj) {
        const int c = tid + 256 * jj;
        if (c < nlds) {
            uint4 qq[4];
            setup_chunk(Pv, base4 + (size_t)c * 7, acc, qq);
#pragma unroll
            for (int k = 0; k < 4; ++k) qsh[c * 4 + k] = qq[k];
        }
    }
    if (have_reg) setup_chunk(Pv, base4 + (size_t)crg * 7, acc, rq);
    for (int c = CACHECH + tid; c < nch; c += 256) {
        uint4 qq[4];
        setup_chunk(Pv, base4 + (size_t)c * 7, acc, qq);
    }
    for (int r = (nch << 2) + tid; r < rows_here; r += 256) {
        float p[KCOLS];
        const float* row = P + (size_t)(row0 + r) * KCOLS;
        for (int j = 0; j < KCOLS; ++j) p[j] = row[j];
        float q[KCOLS], sq;
        softmax10(p, q, sq);
        const float rr = rcp_nr(0.125f * (sq + 1.0f));
        for (int j = 0; j < KCOLS; ++j) acc[j] = fmaf(q[j], rr, acc[j]);
        acc[KCOLS] += rr;
    }

    // block reduce -> publish tagged partial words (tag 1)
#pragma unroll
    for (int j = 0; j < MCOLS; ++j) {
        float v = acc[j];
#pragma unroll
        for (int off = 32; off > 0; off >>= 1) v += __shfl_down(v, off, 64);
        if (lane == 0) wred[wv][j] = (double)v;
    }
    __syncthreads();
    if (tid < MCOLS)
        st_rel(pw + bx * MCOLS + tid,
               mkword(1u, (float)(wred[0][tid] + wred[1][tid] +
                                  wred[2][tid] + wred[3][tid])));

    // ---------------- Sinkhorn loop ---------------------------------------
    double b64[MCOLS];
#pragma unroll
    for (int j = 0; j < MCOLS; ++j) b64[j] = 0.125;
    float bff[MCOLS], bpf[MCOLS];
#pragma unroll
    for (int j = 0; j < MCOLS; ++j) { bff[j] = 0.125f; bpf[j] = 0.125f; }

    for (int it = 1; it <= 50; ++it) {
        const unsigned want = (unsigned)it;
        int stop;
        if (bx == 0) {
            // ---- leader: poll+reduce partials, compute b, broadcast -------
            double c8[MCOLS];
#pragma unroll
            for (int j = 0; j < MCOLS; ++j) c8[j] = 0.0;
            for (int s = tid; s < nb; s += 256) {
                const u64* wp = pw + s * MCOLS;
#pragma unroll
                for (int j = 0; j < MCOLS; ++j) {
                    u64 w;
                    while ((unsigned)((w = ld_rel(wp + j)) >> 32) != want)
                        __builtin_amdgcn_s_sleep(1);
                    c8[j] += (double)__uint_as_float((unsigned)w);
                }
            }
#pragma unroll
            for (int j = 0; j < MCOLS; ++j) {   // fixed f64 tree -> deterministic
                double v = c8[j];
#pragma unroll
                for (int off = 32; off > 0; off >>= 1) v += __shfl_down(v, off, 64);
                if (lane == 0) wred[wv][j] = v;
            }
            __syncthreads();
            if (tid < MCOLS) {
                double c = wred[0][tid] + wred[1][tid] + wred[2][tid] + wred[3][tid];
                c *= inv_n;
                bn_sh[tid] = (tid < KCOLS) ? pow(Pb[tid] / c, fi) : 0.0;
            }
            __syncthreads();
            double err2 = 0.0;
#pragma unroll
            for (int j = 0; j < MCOLS; ++j) {
                const double d = bn_sh[j] - b64[j];
                err2 += d * d;
            }
            stop = (err2 <= 1e-12 || it == 50) ? 1 : 0;
            if (tid < MCOLS)
                st_rel(bw + tid, mkword(want | (stop ? 0x80000000u : 0u),
                                        (float)bn_sh[tid]));
#pragma unroll
            for (int j = 0; j < MCOLS; ++j) {
                bpf[j] = (float)b64[j];
                b64[j] = bn_sh[j];
                bff[j] = (float)b64[j];
            }
        } else {
            // ---- follower: 8 threads poll the 8 broadcast words ----------
            if (tid < MCOLS) {
                u64 w;
                while ((unsigned)(((w = ld_rel(bw + tid)) >> 32) & TAGM) != want)
                    __builtin_amdgcn_s_sleep(2);
                bf_sh[tid] = __uint_as_float((unsigned)w);
                if (tid == 0) stop_sh = (int)(w >> 63);
            }
            __syncthreads();
            stop = stop_sh;
#pragma unroll
            for (int j = 0; j < MCOLS; ++j) {
                bpf[j] = bff[j];
                bff[j] = bf_sh[j];
            }
        }
        if (stop) break;

        // ---- compute pass with new b ----------------------------------
        float a2[MCOLS];
#pragma unroll
        for (int j = 0; j < MCOLS; ++j) a2[j] = 0.0f;
#pragma unroll
        for (int jj = 0; jj < 12; ++jj) {
            const int r = tid + 256 * jj;
            if (r < nlds * 4) cached_row(qsh[r], bff, a2);
        }
        if (have_reg) {
#pragma unroll
            for (int k = 0; k < 4; ++k) cached_row(rq[k], bff, a2);
        }
        for (int c = CACHECH + tid; c < nch; c += 256)
            stream_chunk(Pv, base4 + (size_t)c * 7, bff, a2);
        for (int r = (nch << 2) + tid; r < rows_here; r += 256) {
            float p2[KCOLS];
            const float* row = P + (size_t)(row0 + r) * KCOLS;
            for (int j = 0; j < KCOLS; ++j) p2[j] = row[j];
            float q[KCOLS], sq;
            softmax10(p2, q, sq);
            float dot = bff[KCOLS];
            for (int j = 0; j < KCOLS; ++j) dot = fmaf(q[j], bff[j], dot);
            const float rr = rcp_nr(dot);
            for (int j = 0; j < KCOLS; ++j) a2[j] = fmaf(q[j], rr, a2[j]);
            a2[KCOLS] += rr;
        }

#pragma unroll
        for (int j = 0; j < MCOLS; ++j) {
            float v = a2[j];
#pragma unroll
            for (int off = 32; off > 0; off >>= 1) v += __shfl_down(v, off, 64);
            if (lane == 0) wred[wv][j] = (double)v;
        }
        __syncthreads();
        if (tid < MCOLS)
            st_rel(pw + bx * MCOLS + tid,
                   mkword((unsigned)(it + 1),
                          (float)(wred[0][tid] + wred[1][tid] +
                                  wred[2][tid] + wred[3][tid])));
    }

    // ---------------- final pass: exact f32 q from P, write plan -----------
    float4* Ov = (float4*)out;
    for (int c = tid; c < nch; c += 256)
        final_chunk(Pv, Ov, base4 + (size_t)c * 7, bpf, bff);
    for (int r = (nch << 2) + tid; r < rows_here; r += 256) {
        float p[KCOLS];
        const float* row = P + (size_t)(row0 + r) * KCOLS;
        for (int j = 0; j < KCOLS; ++j) p[j] = row[j];
        float q[KCOLS], sq;
        softmax10(p, q, sq);
        float dot = bpf[KCOLS];
        for (int j = 0; j < KCOLS; ++j) dot = fmaf(q[j], bpf[j], dot);
        const float rr = rcp_nr(dot);
        float* orow = out + (size_t)(row0 + r) * KCOLS;
        for (int j = 0; j < KCOLS; ++j) orow[j] = q[j] * bff[j] * rr;
    }
}

extern "C" void kernel_launch(void* const* d_in, const int* in_sizes, int n_in,
                              void* d_out, int out_size, void* d_ws, size_t ws_size,
                              hipStream_t stream) {
    (void)n_in; (void)out_size;
    const float* P = (const float*)d_in[0];
    float* out = (float*)d_out;
    const int n = in_sizes[0] / KCOLS;

    int dev = 0;
    hipGetDevice(&dev);
    int cus = 0;
    hipDeviceGetAttribute(&cus, hipDeviceAttributeMultiprocessorCount, dev);
    if (cus <= 0) cus = 256;
    int maxb = 0;
    if (hipOccupancyMaxActiveBlocksPerMultiprocessor(&maxb, sinkhorn_v6, 256, 0) != hipSuccess || maxb < 1)
        maxb = 1;

    long long cap = (long long)maxb * cus;
    int nb = NB_PREF;
    if (nb > cap) nb = (int)cap;
    while (nb > 64 && (size_t)((nb * MCOLS + MCOLS) * sizeof(u64)) > ws_size) nb >>= 1;
    if (nb < 2) nb = 2;
    int rpb = (((n + nb - 1) / nb) + 3) & ~3;   // nb=512, n=2^21 -> 4096 exact

    u64* pw = (u64*)d_ws;
    u64* bwv = pw + (size_t)nb * MCOLS;

    void* args[] = {(void*)&P, (void*)&out, (void*)&pw, (void*)&bwv,
                    (void*)&n, (void*)&nb, (void*)&rpb};
    hipLaunchCooperativeKernel((void*)sinkhorn_v6, dim3(nb), dim3(256),
                               args, 0, stream);
}